// Round 14
// baseline (70.967 us; speedup 1.0000x reference)
//
#include <hip/hip_runtime.h>

#define NF    4
#define NCLS  4
#define PLO   256
#define PHI   16384
#define KN    9
#define W27   27
#define CPX   32              // pixels per block
#define TH    5
#define TW    36              // tile cols: j0-2 .. j0+33
#define TSL   (TH * TW)       // 180 float2 slots per split-tile
#define XSL   48              // 4f x 2 cell-rows x 6 cell-cols
#define WARENA_F (NF * CPX * W27)   // 3456 floats = 13824 B

__global__ __launch_bounds__(256, 8) void rect_up_kernel(
    const float* __restrict__ x,         // (B, NF*PLO)
    const float* __restrict__ orog,      // (B, PHI, 2)
    const float* __restrict__ wmap,      // (NCLS, NF, PHI, KN, 3)
    const float* __restrict__ bias_low,  // (NCLS, NF, PLO)
    const float* __restrict__ bias_high, // (NCLS, NF, PHI)
    const float* __restrict__ bias_orog, // (NCLS, 2, PHI)
    const int*   __restrict__ cls_ids,   // (B,)
    const int*   __restrict__ nb,        // (PHI, KN)
    float* __restrict__ out)             // (B, NF, PHI)
{
    // phase 1: weight staging (3456 floats); phase 2 reuses as tiles+xs
    __shared__ float arena[WARENA_F];

    const int bid    = blockIdx.x;
    const int cls    = bid & 3;
    const int chunk  = bid >> 2;             // 0..511
    const int t      = threadIdx.x;
    const int lane64 = t & 63;
    const int px     = t & 31;               // pixel within chunk
    const int f      = (t >> 5) & 3;         // feature
    const int split  = t >> 7;               // 0,1 (wave-uniform)
    const int st     = t & 127;              // stager role within split
    const int p      = chunk * CPX + px;
    const int pi     = chunk >> 2;           // pixel row (uniform per block)
    const int j0     = (chunk & 3) * CPX;    // first column
    const int pj     = j0 + px;

    // ---- (1) weight staging: 864 float4 across 256 threads -------------
    {
        const float* wbase = wmap + ((size_t)(cls * NF) * PHI + chunk * CPX) * W27;
        #pragma unroll
        for (int i = 0; i < 4; ++i) {
            const int idx = t + i * 256;
            if (idx < 864) {
                const int f2 = idx / 216;          // feature slice
                const int rm = idx - f2 * 216;
                const float4* s4 = reinterpret_cast<const float4*>(
                    wbase + (size_t)f2 * PHI * W27);
                reinterpret_cast<float4*>(arena)[idx] = s4[rm];
            }
        }
    }

    // ---- class membership (wave width == BSZ == 64) ---------------------
    const unsigned long long cmask = __ballot(cls_ids[lane64] == cls);
    if (cmask == 0ULL) return;               // block-uniform, pre-barrier
    const int nbc = __popcll(cmask);
    const int R   = (nbc + 1) >> 1;          // lockstep rounds

    // ---- per-split batch scan: every 2nd matching batch -----------------
    unsigned long long m = cmask;
    if (split == 1) m &= m - 1;              // split 1 starts at 2nd bit
    auto nextb = [&]() -> int {
        if (!m) return -1;
        const int bb = __ffsll(m) - 1;
        m &= m - 1;                          // mine
        if (m) m &= m - 1;                   // skip other split's
        return bb;
    };
    int b = nextb();

    // ---- batch-invariant geometry ---------------------------------------
    const int R0 = pi - 2, C0 = j0 - 2;
    const int CR0 = (pi - 2 < 0 ? 0 : pi - 2) >> 3;
    const int CR1 = (pi + 2 > 127 ? 127 : pi + 2) >> 3;
    const int XC0 = (j0 - 2 < 0 ? 0 : j0 - 2) >> 3;
    const int ccl0 = ((pj - 2 < 0 ? 0 : pj - 2) >> 3) - XC0;   // 0..4

    int ldsoff[KN];
    unsigned selpack = 0;                    // 2 bits per k
    #pragma unroll
    for (int k = 0; k < KN; ++k) {
        const int n  = nb[p * KN + k];
        const int ni = n >> 7, nj = n & 127; // within [pi±2],[pj±2]
        ldsoff[k] = (ni - R0) * TW + (nj - C0);
        const unsigned rr = ((ni >> 3) != CR0) ? 2u : 0u;
        const unsigned cc = ((nj >> 3) != (XC0 + ccl0)) ? 1u : 0u;
        selpack |= (rr | cc) << (2 * k);
    }

    // ---- stager roles (within my split's 128 threads) -------------------
    const bool tileR1 = (st < TSL - 128);    // slot 128+st
    const bool xsR    = (st < XSL);
    int gO0, gO1 = 0; float bo00, bo01, bo10 = 0.f, bo11 = 0.f;
    {
        const int r = st / TW, c = st - (st / TW) * TW;   // slot st (<180)
        int nr = R0 + r; nr = nr < 0 ? 0 : (nr > 127 ? 127 : nr);
        int nc = C0 + c; nc = nc < 0 ? 0 : (nc > 127 ? 127 : nc);
        const int ns = nr * 128 + nc;
        gO0  = ns * 8;
        bo00 = bias_orog[(cls * 2 + 0) * PHI + ns];
        bo01 = bias_orog[(cls * 2 + 1) * PHI + ns];
    }
    if (tileR1) {
        const int s = 128 + st;
        const int r = s / TW, c = s - (s / TW) * TW;
        int nr = R0 + r; nr = nr < 0 ? 0 : (nr > 127 ? 127 : nr);
        int nc = C0 + c; nc = nc < 0 ? 0 : (nc > 127 ? 127 : nc);
        const int ns = nr * 128 + nc;
        gO1  = ns * 8;
        bo10 = bias_orog[(cls * 2 + 0) * PHI + ns];
        bo11 = bias_orog[(cls * 2 + 1) * PHI + ns];
    }
    int xIdx = 0; float xbl = 0.f;
    if (xsR) {                               // xs: (f, rr, cc) -> f*12+rr*6+cc
        const int ff = st / 12, q = st - (st / 12) * 12, rr = q / 6, c2 = q - (q / 6) * 6;
        const int crow = rr ? CR1 : CR0;
        int col = XC0 + c2; col = col > 15 ? 15 : col;
        xIdx = ff * PLO + crow * 16 + col;
        xbl  = bias_low[cls * (NF * PLO) + xIdx];
    }

    // ---- first batch's loads (fly under the weight stream) --------------
    float2 v0 = make_float2(0.f, 0.f), v1 = make_float2(0.f, 0.f);
    float xv = 0.f;
    if (b >= 0) {
        const char* ob = (const char*)orog + (size_t)b * (PHI * 8);
        v0 = *reinterpret_cast<const float2*>(ob + gO0);
        if (tileR1) v1 = *reinterpret_cast<const float2*>(ob + gO1);
        if (xsR)    xv = x[b * (NF * PLO) + xIdx];
    }
    const float accB = bias_high[(cls * NF + f) * PHI + p];

    __syncthreads();                         // weights staged

    // ---- unpack my (px, f) weights + 9->4 y-weight collapse -------------
    float w1[KN], w2[KN], wcy[4] = {0.f, 0.f, 0.f, 0.f};
    #pragma unroll
    for (int k = 0; k < KN; ++k) {
        const int base = f * (CPX * W27) + px * W27 + 3 * k;
        const float w0 = arena[base];
        w1[k] = arena[base + 1];
        w2[k] = arena[base + 2];
        const unsigned sk = (selpack >> (2 * k)) & 3u;
        #pragma unroll
        for (int j = 0; j < 4; ++j)
            wcy[j] += (sk == (unsigned)j) ? w0 : 0.f;
    }

    __syncthreads();                         // arena reads done -> tiles

    // tile-phase layout (floats): tile(s,q) float2[180] at (s*2+q)*360;
    //                             xs(s,q)  float [48]  at 1440+(s*2+q)*48
    if (b >= 0) {
        float2* tp = reinterpret_cast<float2*>(arena) + (split * 2 + 0) * 180;
        tp[st] = make_float2(v0.x - bo00, v0.y - bo01);
        if (tileR1) tp[128 + st] = make_float2(v1.x - bo10, v1.y - bo11);
        if (xsR) arena[1440 + (split * 2 + 0) * 48 + st] = xv - xbl;
    }
    __syncthreads();

    // ---- main loop: lockstep rounds, per-split dbuf, 1 barrier/round ----
    int cur = 0;
    for (int r = 0; r < R; ++r) {
        const int bn = nextb();
        if (bn >= 0) {                       // issue next batch's loads
            const char* ob = (const char*)orog + (size_t)bn * (PHI * 8);
            v0 = *reinterpret_cast<const float2*>(ob + gO0);
            if (tileR1) v1 = *reinterpret_cast<const float2*>(ob + gO1);
            if (xsR)    xv = x[bn * (NF * PLO) + xIdx];
        }

        if (b >= 0) {                        // compute current batch
            const float2* tp = reinterpret_cast<const float2*>(arena)
                               + (split * 2 + cur) * 180;
            const float* xsp = arena + 1440 + (split * 2 + cur) * 48;
            const int xb0 = f * 12 + ccl0;
            float acc = accB
                + xsp[xb0]     * wcy[0]
                + xsp[xb0 + 1] * wcy[1]
                + xsp[xb0 + 6] * wcy[2]
                + xsp[xb0 + 7] * wcy[3];
            #pragma unroll
            for (int k = 0; k < KN; ++k) {
                const float2 o = tp[ldsoff[k]];
                acc += o.x * w1[k] + o.y * w2[k];
            }
            out[((size_t)b * NF + f) * PHI + p] = acc;
        }

        if (bn >= 0) {                       // write next into other buffer
            float2* tp = reinterpret_cast<float2*>(arena)
                         + (split * 2 + (cur ^ 1)) * 180;
            tp[st] = make_float2(v0.x - bo00, v0.y - bo01);
            if (tileR1) tp[128 + st] = make_float2(v1.x - bo10, v1.y - bo11);
            if (xsR) arena[1440 + (split * 2 + (cur ^ 1)) * 48 + st] = xv - xbl;
        }
        __syncthreads();
        b = bn; cur ^= 1;
    }
}

extern "C" void kernel_launch(void* const* d_in, const int* in_sizes, int n_in,
                              void* d_out, int out_size, void* d_ws, size_t ws_size,
                              hipStream_t stream) {
    const float* x         = (const float*)d_in[0];
    const float* orog      = (const float*)d_in[1];
    const float* wmap      = (const float*)d_in[2];
    const float* bias_low  = (const float*)d_in[3];
    const float* bias_high = (const float*)d_in[4];
    const float* bias_orog = (const float*)d_in[5];
    const int*   cls_ids   = (const int*)d_in[6];
    const int*   nb        = (const int*)d_in[7];
    float* out = (float*)d_out;

    // grid: NCLS x 512 chunks of 32 pixels = 2048 blocks; 8 blocks/CU.
    // thread (px,f,split) = (t&31, (t>>5)&3, t>>7); batches split across halves.
    dim3 grid(NCLS * (PHI / CPX));
    dim3 block(256);
    rect_up_kernel<<<grid, block, 0, stream>>>(
        x, orog, wmap, bias_low, bias_high, bias_orog, cls_ids, nb, out);
}

// Round 15
// 32.496 us; speedup vs baseline: 2.1839x; 2.1839x over previous
//
#include <hip/hip_runtime.h>

#define NF    4
#define NCLS  4
#define PLO   256
#define PHI   16384
#define KN    9
#define W27   27
#define CPX   64              // pixels per block (half a 128-row)
#define TH    5
#define TW    68              // tile cols j0-2 .. j0+65
#define TSL   (TH * TW)       // 340 float2 slots per batch-tile
#define XSL   40              // 2 features x 2 cell-rows x 10 cell-cols
#define TSTR  344             // float2 stride per tile buffer (4-slot pad)
#define XSBASE (4 * TSTR * 2) // float offset of xs area = 2752
#define ARENA_F 3456          // floats (= 864 float4 = 13824 B)

__global__ __launch_bounds__(256, 4) void rect_up_kernel(
    const float* __restrict__ x,         // (B, NF*PLO)
    const float* __restrict__ orog,      // (B, PHI, 2)
    const float* __restrict__ wmap,      // (NCLS, NF, PHI, KN, 3)
    const float* __restrict__ bias_low,  // (NCLS, NF, PLO)
    const float* __restrict__ bias_high, // (NCLS, NF, PHI)
    const float* __restrict__ bias_orog, // (NCLS, 2, PHI)
    const int*   __restrict__ cls_ids,   // (B,)
    const int*   __restrict__ nb,        // (PHI, KN)
    float* __restrict__ out)             // (B, NF, PHI)
{
    // phase 1: 2-feature weight staging (3456 floats); phase 2: tiles+xs
    __shared__ float arena[ARENA_F];

    const int bid    = blockIdx.x;
    const int cls    = bid & 3;
    const int chunk  = (bid >> 2) & 255;     // 0..255
    const int fpair  = bid >> 10;            // 0,1
    const int t      = threadIdx.x;
    const int lane   = t & 63;               // px
    const int flocal = (t >> 6) & 1;
    const int f      = fpair * 2 + flocal;   // global feature
    const int sp     = t >> 7;               // batch-split half
    const int st     = t & 127;              // stager role within half
    const int p      = chunk * CPX + lane;
    const int pi     = chunk >> 1;           // pixel row (uniform)
    const int j0     = (chunk & 1) * 64;
    const int pj     = j0 + lane;

    // ---- (1) weight staging: 864 float4 (2 features) across 256 thr ----
    {
        const float* wbase = wmap +
            ((size_t)(cls * NF + fpair * 2) * PHI + chunk * CPX) * W27;
        #pragma unroll
        for (int i = 0; i < 4; ++i) {
            const int idx = t + i * 256;
            if (idx < 864) {
                const int f2 = idx / 432;          // feature slice (432 f4 each)
                const int rm = idx - f2 * 432;
                const float4* s4 = reinterpret_cast<const float4*>(
                    wbase + (size_t)f2 * PHI * W27);
                reinterpret_cast<float4*>(arena)[idx] = s4[rm];
            }
        }
    }

    // ---- class membership (wave width == BSZ == 64) ---------------------
    const unsigned long long cmask = __ballot(cls_ids[lane] == cls);
    if (cmask == 0ULL) return;               // block-uniform, pre-barrier
    const int nbc = __popcll(cmask);
    const int R   = (nbc + 1) >> 1;          // lockstep rounds

    // ---- per-half batch scan: even/odd matching batches -----------------
    unsigned long long m = cmask;
    if (sp == 1) m &= m - 1;
    auto nextb = [&]() -> int {
        if (!m) return -1;
        const int bb = __ffsll(m) - 1;
        m &= m - 1;                          // mine
        if (m) m &= m - 1;                   // other half's
        return bb;
    };
    int b = nextb();

    // ---- batch-invariant geometry ---------------------------------------
    const int R0 = pi - 2, C0 = j0 - 2;
    const int CR0 = (pi - 2 < 0 ? 0 : pi - 2) >> 3;
    const int CR1 = (pi + 2 > 127 ? 127 : pi + 2) >> 3;
    const int XC0 = (j0 - 2 < 0 ? 0 : j0 - 2) >> 3;
    const int ccl0 = ((pj - 2 < 0 ? 0 : pj - 2) >> 3) - XC0;   // 0..9

    int ldsoff[KN], sel[KN];
    #pragma unroll
    for (int k = 0; k < KN; ++k) {
        const int n  = nb[p * KN + k];
        const int ni = n >> 7, nj = n & 127;
        ldsoff[k] = (ni - R0) * TW + (nj - C0);
        const int rr = ((ni >> 3) != CR0) ? 1 : 0;
        const int cc = ((nj >> 3) != (XC0 + ccl0)) ? 1 : 0;
        sel[k] = rr * 2 + cc;
    }

    // ---- stager roles (my half's 128 threads; 340 tile + 40 xs slots) ---
    const bool seg2 = (st < TSL - 256);      // slot 256+st
    const bool xsR  = (st < XSL);
    int gO0, gO1, gO2 = 0;
    float bo00, bo01, bo10, bo11, bo20 = 0.f, bo21 = 0.f;
    {
        const int r = st / TW, c = st - (st / TW) * TW;       // slot st
        int nr = R0 + r; nr = nr < 0 ? 0 : (nr > 127 ? 127 : nr);
        int nc = C0 + c; nc = nc < 0 ? 0 : (nc > 127 ? 127 : nc);
        const int ns = nr * 128 + nc;
        gO0  = ns * 8;
        bo00 = bias_orog[(cls * 2 + 0) * PHI + ns];
        bo01 = bias_orog[(cls * 2 + 1) * PHI + ns];
    }
    {
        const int s = 128 + st;                                // slot 128+st
        const int r = s / TW, c = s - (s / TW) * TW;
        int nr = R0 + r; nr = nr < 0 ? 0 : (nr > 127 ? 127 : nr);
        int nc = C0 + c; nc = nc < 0 ? 0 : (nc > 127 ? 127 : nc);
        const int ns = nr * 128 + nc;
        gO1  = ns * 8;
        bo10 = bias_orog[(cls * 2 + 0) * PHI + ns];
        bo11 = bias_orog[(cls * 2 + 1) * PHI + ns];
    }
    if (seg2) {                                                // slot 256+st
        const int s = 256 + st;
        const int r = s / TW, c = s - (s / TW) * TW;
        int nr = R0 + r; nr = nr < 0 ? 0 : (nr > 127 ? 127 : nr);
        int nc = C0 + c; nc = nc < 0 ? 0 : (nc > 127 ? 127 : nc);
        const int ns = nr * 128 + nc;
        gO2  = ns * 8;
        bo20 = bias_orog[(cls * 2 + 0) * PHI + ns];
        bo21 = bias_orog[(cls * 2 + 1) * PHI + ns];
    }
    int xIdx = 0; float xbl = 0.f;
    if (xsR) {                               // xs: (ff,rr,cc) -> ff*20+rr*10+cc
        const int ff = st / 20, q = st - (st / 20) * 20;
        const int rr = q / 10, c2 = q - (q / 10) * 10;
        const int crow = rr ? CR1 : CR0;
        int col = XC0 + c2; col = col > 15 ? 15 : col;
        xIdx = (fpair * 2 + ff) * PLO + crow * 16 + col;
        xbl  = bias_low[cls * (NF * PLO) + xIdx];
    }

    // ---- first batch's loads (fly under the weight stream) --------------
    float2 v0 = {}, v1 = {}, v2 = {}; float xv = 0.f;
    if (b >= 0) {
        const char* ob = (const char*)orog + (size_t)b * (PHI * 8);
        v0 = *reinterpret_cast<const float2*>(ob + gO0);
        v1 = *reinterpret_cast<const float2*>(ob + gO1);
        if (seg2) v2 = *reinterpret_cast<const float2*>(ob + gO2);
        if (xsR)  xv = x[b * (NF * PLO) + xIdx];
    }
    const float accB = bias_high[(cls * NF + f) * PHI + p];

    __syncthreads();                         // weights staged

    // ---- unpack my (flocal, px) weights + 9->4 y-weight collapse --------
    float w1[KN], w2[KN], wcy[4] = {0.f, 0.f, 0.f, 0.f};
    #pragma unroll
    for (int k = 0; k < KN; ++k) {
        const int base = flocal * (CPX * W27) + lane * W27 + 3 * k;
        const float w0 = arena[base];
        w1[k] = arena[base + 1];
        w2[k] = arena[base + 2];
        #pragma unroll
        for (int j = 0; j < 4; ++j)
            wcy[j] += (sel[k] == j) ? w0 : 0.f;
    }

    __syncthreads();                         // arena reads done -> tile phase

    // tile phase layout: tile(sp,q) float2[TSTR] at (sp*2+q)*TSTR;
    //                    xs(sp,q) float[48] at XSBASE + (sp*2+q)*48
    if (b >= 0) {
        float2* tp = reinterpret_cast<float2*>(arena) + (sp * 2 + 0) * TSTR;
        tp[st]       = make_float2(v0.x - bo00, v0.y - bo01);
        tp[128 + st] = make_float2(v1.x - bo10, v1.y - bo11);
        if (seg2) tp[256 + st] = make_float2(v2.x - bo20, v2.y - bo21);
        if (xsR)  arena[XSBASE + (sp * 2 + 0) * 48 + st] = xv - xbl;
    }
    __syncthreads();

    // ---- main loop: lockstep rounds, per-half dbuf, 1 barrier/round -----
    int cur = 0;
    for (int r = 0; r < R; ++r) {
        const int bn = nextb();
        if (bn >= 0) {                       // issue next batch's loads
            const char* ob = (const char*)orog + (size_t)bn * (PHI * 8);
            v0 = *reinterpret_cast<const float2*>(ob + gO0);
            v1 = *reinterpret_cast<const float2*>(ob + gO1);
            if (seg2) v2 = *reinterpret_cast<const float2*>(ob + gO2);
            if (xsR)  xv = x[bn * (NF * PLO) + xIdx];
        }

        if (b >= 0) {                        // compute current batch
            const float2* tp = reinterpret_cast<const float2*>(arena)
                               + (sp * 2 + cur) * TSTR;
            const float* xsp = arena + XSBASE + (sp * 2 + cur) * 48;
            const int xb0 = flocal * 20 + ccl0;
            float acc = accB
                + xsp[xb0]      * wcy[0]
                + xsp[xb0 + 1]  * wcy[1]
                + xsp[xb0 + 10] * wcy[2]
                + xsp[xb0 + 11] * wcy[3];
            #pragma unroll
            for (int k = 0; k < KN; ++k) {
                const float2 o = tp[ldsoff[k]];
                acc += o.x * w1[k] + o.y * w2[k];
            }
            out[((size_t)b * NF + f) * PHI + p] = acc;
        }

        if (bn >= 0) {                       // write next into other buffer
            float2* tp = reinterpret_cast<float2*>(arena)
                         + (sp * 2 + (cur ^ 1)) * TSTR;
            tp[st]       = make_float2(v0.x - bo00, v0.y - bo01);
            tp[128 + st] = make_float2(v1.x - bo10, v1.y - bo11);
            if (seg2) tp[256 + st] = make_float2(v2.x - bo20, v2.y - bo21);
            if (xsR)  arena[XSBASE + (sp * 2 + (cur ^ 1)) * 48 + st] = xv - xbl;
        }
        __syncthreads();
        b = bn; cur ^= 1;
    }
}

extern "C" void kernel_launch(void* const* d_in, const int* in_sizes, int n_in,
                              void* d_out, int out_size, void* d_ws, size_t ws_size,
                              hipStream_t stream) {
    const float* x         = (const float*)d_in[0];
    const float* orog      = (const float*)d_in[1];
    const float* wmap      = (const float*)d_in[2];
    const float* bias_low  = (const float*)d_in[3];
    const float* bias_high = (const float*)d_in[4];
    const float* bias_orog = (const float*)d_in[5];
    const int*   cls_ids   = (const int*)d_in[6];
    const int*   nb        = (const int*)d_in[7];
    float* out = (float*)d_out;

    // grid: NCLS x 256 chunks x 2 feature-pairs = 2048 blocks (8/CU).
    // thread = (px=lane, flocal=(t>>6)&1, sp=t>>7); weights single-fetch.
    dim3 grid(NCLS * (PHI / CPX) * 2);
    dim3 block(256);
    rect_up_kernel<<<grid, block, 0, stream>>>(
        x, orog, wmap, bias_low, bias_high, bias_orog, cls_ids, nb, out);
}